// Round 3
// baseline (210.204 us; speedup 1.0000x reference)
//
#include <hip/hip_runtime.h>
#include <stdint.h>
#include <math.h>

typedef unsigned long long u64;
typedef unsigned int u32;

#define NPI   360000
#define B_IMG 8
#define PRE   1000
#define POST  300
#define CAP   4096
#define NMSF  0.7f
#define IMG_W 800.0f
#define IMG_H 800.0f

#define NBIN    4096          // 12-bit sortable-key histogram
#define KSHIFT  20            // fkey >> 20 -> 12-bit bin
#define NGRP    64            // coarse groups (64 bins each)
#define CHUNK_H 30            // hist blocks per image (divides 90000)
#define F4PB_H  (NPI / 4 / CHUNK_H)   // 3000
#define CHUNK_C 48            // compact blocks per image
#define F4PB_C  (NPI / 4 / CHUNK_C)   // 1875
#define EPB_C   (NPI / CHUNK_C)       // 7500
#define LBUF    1024          // per-block candidate buffer

// ---- workspace layout (bytes) ----
#define CNT_OFF     0                 // 8*4 = 32
#define VALID_OFF   256               // 8*16*8 = 1024          -> 1280
#define PHIST_OFF   4096              // 8*30*4096*4 = 3932160  -> 3936256
#define PCOARSE_OFF 3936256           // 8*30*64*4   = 61440    -> 3997696
#define BOX_OFF     3997696           // 8*1000*16   = 128000   -> 4125696
#define SCORE_OFF   4125696           // 8*1000*4    = 32000    -> 4157696
#define CAND_OFF    4157696           // 8*4096*8    = 262144   -> 4419840
#define MASK_OFF    4419840           // 8*1000*16*8 = 1024000  -> 5443840

#define LDSROWS 496
#define NMS_T   320
#define RBLK    16            // rank blocks per image (256 candidate slots each)

__device__ __forceinline__ u32 fkey(float f) {
  u32 u = __float_as_uint(f);
  return (u & 0x80000000u) ? ~u : (u | 0x80000000u);  // ascending-order bits
}
__device__ __forceinline__ u64 rl64(u64 v, int lane) {
  u32 lo = (u32)__builtin_amdgcn_readlane((int)(u32)v, lane);
  u32 hi = (u32)__builtin_amdgcn_readlane((int)(u32)(v >> 32), lane);
  return ((u64)hi << 32) | lo;
}
__device__ __forceinline__ u64 sx64(u64 v, int m) {
  u32 lo = (u32)__shfl_xor((int)(u32)v, m, 64);
  u32 hi = (u32)__shfl_xor((int)(u32)(v >> 32), m, 64);
  return ((u64)hi << 32) | lo;
}

// ---- K1: per-(image,chunk) LDS histogram with 4-way salted sub-counters
//      (cuts intra-wave same-address atomic serialization 64 -> <=16-way).
//      Folds at flush; coarse sums via wave butterfly. No global atomics. ----
__global__ __launch_bounds__(256) void k_hist(const float* __restrict__ logits,
                                              u32* __restrict__ phist,
                                              u32* __restrict__ pcoarse,
                                              u32* __restrict__ cnt,
                                              u64* __restrict__ validw) {
  __shared__ u32 h[4 * NBIN];         // 64 KB: 4 salted segments
  const int img = blockIdx.y, c = blockIdx.x;
  const int tid = threadIdx.x;
  for (int i = tid; i < 4 * NBIN; i += 256) h[i] = 0;
  __syncthreads();
  const int salt = ((tid >> 4) & 3) * NBIN;   // lanes 0-15/16-31/32-47/48-63 -> seg 0..3
  const float4* L = (const float4*)(logits + (size_t)img * NPI) + (size_t)c * F4PB_H;
  for (int i = tid; i < F4PB_H; i += 256) {
    float4 v = L[i];
    atomicAdd(&h[salt + (fkey(v.x) >> KSHIFT)], 1u);
    atomicAdd(&h[salt + (fkey(v.y) >> KSHIFT)], 1u);
    atomicAdd(&h[salt + (fkey(v.z) >> KSHIFT)], 1u);
    atomicAdd(&h[salt + (fkey(v.w) >> KSHIFT)], 1u);
  }
  __syncthreads();
  // fold segments -> fine partial hist (streaming store) + coarse via butterfly
  u32* P = phist + ((size_t)img * CHUNK_H + c) * NBIN;
  u32* PC = pcoarse + ((size_t)img * CHUNK_H + c) * NGRP;
  const int lane = tid & 63;
#pragma unroll
  for (int k = 0; k < NBIN / 256; k++) {      // 16 iterations
    int i = k * 256 + tid;
    u32 v = h[i] + h[NBIN + i] + h[2 * NBIN + i] + h[3 * NBIN + i];
    P[i] = v;
    u32 s = v;                                // wave covers one contiguous 64-bin group
#pragma unroll
    for (int m = 1; m < 64; m <<= 1) s += (u32)__shfl_xor((int)s, m, 64);
    if (lane == 0) PC[i >> 6] = s;            // i>>6 uniform across the wave
  }
  // zero accumulators consumed by later dispatches (hist completes first)
  if (c == 0) {
    if (tid < 16) validw[img * 16 + tid] = 0;
    if (img == 0 && tid < B_IMG) cnt[tid] = 0;
  }
}

// ---- K2: compact candidates >= threshold; threshold computed in-block via
//      two-level (coarse group -> fine bin) suffix scan over partial hists.
//      Logit prefetch issued BEFORE the select so select hides load latency. ----
__global__ __launch_bounds__(256) void k_compact(const float* __restrict__ logits,
                                                 const u32* __restrict__ phist,
                                                 const u32* __restrict__ pcoarse,
                                                 u32* __restrict__ cnt,
                                                 u64* __restrict__ cand) {
  __shared__ u64 buf[LBUF];
  __shared__ u32 bcnt;
  __shared__ u32 gbase;
  __shared__ int stb;
  const int img = blockIdx.y, c = blockIdx.x;
  const int t = threadIdx.x;
  if (t == 0) { bcnt = 0; stb = 0; }
  // ---- prefetch this block's logits into registers (independent of select) ----
  const float4* L = (const float4*)(logits + (size_t)img * NPI) + (size_t)c * F4PB_C;
  float4 r[8];
#pragma unroll
  for (int k = 0; k < 8; k++) {
    int i = t + k * 256;
    if (i < F4PB_C) r[k] = L[i];
  }
  // ---- inline select (wave 0 only; overlaps prefetch latency) ----
  if (t < 64) {
    const u32* PC = pcoarse + (size_t)img * CHUNK_H * NGRP;
    u32 cg = 0;
    for (int cc = 0; cc < CHUNK_H; cc++) cg += PC[cc * NGRP + t];
    u32 suf = cg;
#pragma unroll
    for (int off = 1; off < 64; off <<= 1) {
      u32 o = (u32)__shfl_down((int)suf, off, 64);
      if (t + off < 64) suf += o;
    }
    u32 sx = suf - cg;                       // count in groups > t
    u64 bal = __ballot(suf >= (u32)PRE && sx < (u32)PRE);
    if (bal) {                               // crossing group exists
      int gc = __builtin_ctzll(bal);
      u32 s_above = (u32)__shfl((int)sx, gc, 64);   // count in groups > gc
      const u32* P = phist + (size_t)img * CHUNK_H * NBIN + gc * (NBIN / NGRP);
      u32 fb = 0;
      for (int cc = 0; cc < CHUNK_H; cc++) fb += P[(size_t)cc * NBIN + t];
      u32 fsuf = fb;
#pragma unroll
      for (int off = 1; off < 64; off <<= 1) {
        u32 o = (u32)__shfl_down((int)fsuf, off, 64);
        if (t + off < 64) fsuf += o;
      }
      u32 fincl = fsuf + s_above;            // count(key-bin >= gc*64+t)
      u32 fexcl = fincl - fb;
      if (fincl >= (u32)PRE && fexcl < (u32)PRE) stb = gc * (NBIN / NGRP) + t;
    }
  }
  __syncthreads();
  const int tb = stb;
  const int ebase = c * EPB_C;
#pragma unroll
  for (int k = 0; k < 8; k++) {
    int i = t + k * 256;
    if (i < F4PB_C) {
      float xs[4] = {r[k].x, r[k].y, r[k].z, r[k].w};
#pragma unroll
      for (int q = 0; q < 4; q++) {
        float x = xs[q];
        if ((int)(fkey(x) >> KSHIFT) >= tb) {
          // fp32 sigmoid with correctly-rounded exp: replicates numpy f32
          // tie structure exactly (verified: absmax 0.0)
          float ef = (float)exp(-(double)x);
          float sg = 1.0f / (1.0f + ef);
          u32 e = (u32)(ebase + 4 * i + q);
          u32 p = atomicAdd(&bcnt, 1u);
          if (p < LBUF)
            buf[p] = ((u64)fkey(sg) << 32) | (u64)(0xFFFFFFFFu - e);
        }
      }
    }
  }
  __syncthreads();
  if (t == 0) {
    u32 m = bcnt < LBUF ? bcnt : LBUF;
    bcnt = m;
    gbase = atomicAdd(&cnt[img], m);
  }
  __syncthreads();
  const u32 m = bcnt, gb = gbase;
  for (u32 j = t; j < m; j += 256) {
    u32 pos = gb + j;
    if (pos < CAP) cand[img * CAP + pos] = buf[j];
  }
}

// ---- K3: exact rank + decode/clip. Count loop sliced 4-ways across the
//      block's waves (loop length n/4, partials reduced in LDS). ----
__device__ __forceinline__ void emit_row(
    int img, int row, u64 key,
    const float* __restrict__ deltas, const float* __restrict__ anchors,
    float4* __restrict__ boxes, float* __restrict__ scores, u64* __restrict__ validw) {
  u32 hi  = (u32)(key >> 32);
  u32 idx = 0xFFFFFFFFu - (u32)(key & 0xFFFFFFFFu);
  u32 su  = (hi & 0x80000000u) ? (hi ^ 0x80000000u) : ~hi;
  float sc = __uint_as_float(su);
  size_t off = (size_t)img * NPI + idx;
  float4 d = ((const float4*)deltas)[off];
  float4 a = ((const float4*)anchors)[off];
  float aw = a.z - a.x, ah = a.w - a.y;
  float acx = a.x + 0.5f * aw, acy = a.y + 0.5f * ah;
  float cx = d.x * aw + acx, cy = d.y * ah + acy;
  float w = expf(d.z) * aw, h = expf(d.w) * ah;
  float x1 = cx - 0.5f * w, y1 = cy - 0.5f * h;
  float x2 = cx + 0.5f * w, y2 = cy + 0.5f * h;
  x1 = fminf(fmaxf(x1, 0.f), IMG_W);
  y1 = fminf(fmaxf(y1, 0.f), IMG_H);
  x2 = fminf(fmaxf(x2, 0.f), IMG_W);
  y2 = fminf(fmaxf(y2, 0.f), IMG_H);
  boxes[img * PRE + row]  = make_float4(x1, y1, x2, y2);
  scores[img * PRE + row] = sc;
  if (((x2 - x1) >= 1e-3f) && ((y2 - y1) >= 1e-3f))
    atomicOr(&validw[img * 16 + (row >> 6)], 1ull << (row & 63));
}

__global__ __launch_bounds__(256) void k_rank(
    const float* __restrict__ deltas, const float* __restrict__ anchors,
    const u32* __restrict__ cnt, const u64* __restrict__ cand,
    float4* __restrict__ boxes, float* __restrict__ scores, u64* __restrict__ validw) {
  __shared__ u64 skey[CAP];           // 32 KB
  __shared__ u32 pc[4][256];          // 4 KB: per-wave partial counts
  const int img = blockIdx.y;
  int n = (int)cnt[img];
  if (n > CAP) n = CAP;
  const int base = blockIdx.x * 256;  // this block's candidate-slot window
  if (base >= n) return;              // block-uniform early exit
  for (int i = threadIdx.x; i < n; i += 256) skey[i] = cand[img * CAP + i];
  __syncthreads();
  const int w = threadIdx.x >> 6, l = threadIdx.x & 63;
  const int r0 = base + l, r1 = r0 + 64, r2 = r0 + 128, r3 = r0 + 192;
  u64 k0 = (r0 < n) ? skey[r0] : 0ull;
  u64 k1 = (r1 < n) ? skey[r1] : 0ull;
  u64 k2 = (r2 < n) ? skey[r2] : 0ull;
  u64 k3 = (r3 < n) ? skey[r3] : 0ull;
  int c0 = 0, c1 = 0, c2 = 0, c3 = 0;
  const int js = (w * n) >> 2, je = ((w + 1) * n) >> 2;   // disjoint cover of [0,n)
  for (int j = js; j < je; j++) {
    u64 kj = skey[j];                 // same address across wave -> LDS broadcast
    c0 += (kj > k0); c1 += (kj > k1); c2 += (kj > k2); c3 += (kj > k3);
  }
  pc[w][l]       = (u32)c0;
  pc[w][l + 64]  = (u32)c1;
  pc[w][l + 128] = (u32)c2;
  pc[w][l + 192] = (u32)c3;
  __syncthreads();
  const int t = threadIdx.x;
  const int rr = base + t;
  if (rr < n) {
    int c = (int)(pc[0][t] + pc[1][t] + pc[2][t] + pc[3][t]);
    if (c < PRE) emit_row(img, c, skey[rr], deltas, anchors, boxes, scores, validw);
  }
}

// ---- K4: suppression bitmask via LDS broadcast (zero bank conflicts) ----
__global__ __launch_bounds__(1024) void k_iou(const float4* __restrict__ boxes,
                                              u64* __restrict__ mask) {
  __shared__ float4 sb[1024];
  __shared__ float  sa[1024];
  const int img = blockIdx.y;
  const int tid = threadIdx.x;
  {
    float4 b = (tid < PRE) ? boxes[img * PRE + tid]
                           : make_float4(0.f, 0.f, 0.f, 0.f);
    sb[tid] = b;
    sa[tid] = (b.z - b.x) * (b.w - b.y);
  }
  __syncthreads();
  const int lane = tid & 63;
  const int wv   = tid >> 6;          // word index 0..15
  const int i    = blockIdx.x * 64 + lane;   // row
  const bool rowok = (i < PRE);
  const float4 bi = sb[blockIdx.x * 64 + lane];
  const float  ai = sa[blockIdx.x * 64 + lane];
  const int cbase = wv << 6;
  u64 bits = 0;
#pragma unroll
  for (int k = 0; k < 64; k++) {
    int c = cbase + k;
    float4 bc = sb[c];                // broadcast read
    float ac  = sa[c];
    float ltx = fmaxf(bi.x, bc.x), lty = fmaxf(bi.y, bc.y);
    float rbx = fminf(bi.z, bc.z), rby = fminf(bi.w, bc.w);
    float iw = fmaxf(rbx - ltx, 0.f), ih = fmaxf(rby - lty, 0.f);
    float inter = iw * ih;
    float iou = inter / (ai + ac - inter + 1e-9f);  // IEEE div, matches ref
    bits |= (iou > NMSF) ? (1ull << k) : 0ull;
  }
  int d = i - cbase;
  u64 gtmask = (d < 0) ? ~0ull : ((d >= 63) ? 0ull : (~0ull << (d + 1)));
  int rem = PRE - cbase;
  u64 tmask = (rem >= 64) ? ~0ull : ((rem <= 0) ? 0ull : ((1ull << rem) - 1ull));
  bits &= gtmask & tmask;
  if (rowok) mask[((size_t)img * PRE + i) * 16 + wv] = bits;
}

// ---- K5: chunked greedy scan — scalar in-chunk decisions via readlane ----
__global__ __launch_bounds__(NMS_T) void k_nms(
    const u64* __restrict__ mask, const u64* __restrict__ validw,
    const float4* __restrict__ boxes, const float* __restrict__ scores,
    float* __restrict__ out) {
  __shared__ u64 smask[LDSROWS * 16];
  __shared__ int skeeplist[POST];
  __shared__ int skept;
  const int img = blockIdx.x;
  const int tid = threadIdx.x;
  const u64* M = mask + (size_t)img * PRE * 16;
  u64 diag[16];
  if (tid < 64) {
#pragma unroll
    for (int cc = 0; cc < 16; cc++) {
      int row = cc * 64 + tid;
      diag[cc] = (row < PRE) ? M[(size_t)row * 16 + cc] : 0ull;
    }
  }
  for (int e = tid; e < LDSROWS * 16; e += NMS_T) smask[e] = M[e];
  __syncthreads();
  if (tid < 64) {
    const int lane = tid;
    const int w = lane & 15, g = lane >> 4;
    u64 rem = ~0ull;
    if (lane < 16) {
      rem = ~validw[img * 16 + lane];
      if (lane == 15) rem |= 0xFFFFFF0000000000ull;  // rows 1000..1023 invalid
    }
    int kept = 0;
#pragma unroll
    for (int cc = 0; cc < 16; cc++) {
      u64 alive = ~rl64(rem, cc);      // wave-uniform
      int kept0 = kept;
      while (alive != 0ull && kept < POST) {
        int r = __builtin_ctzll(alive);
        if (lane == 0) skeeplist[kept] = cc * 64 + r;
        kept++;
        u64 sup = rl64(diag[cc], r);   // row's in-chunk suppression word
        alive &= ~sup;
        alive &= ~(1ull << r);
      }
      int nc = kept - kept0;
      if (nc > 0 && kept < POST && cc < 15) {
        u64 part = 0;
        for (int j = g; j < nc; j += 4) {
          int row = skeeplist[kept0 + j];
          part |= (row < LDSROWS) ? smask[row * 16 + w] : M[(size_t)row * 16 + w];
        }
        part |= sx64(part, 16);
        part |= sx64(part, 32);
        rem |= part;                   // only lanes <16 meaningful
      }
      if (kept >= POST) break;
    }
    if (lane == 0) skept = kept;
  }
  __syncthreads();
  if (tid < POST) {
    float4 bx = make_float4(0.f, 0.f, 0.f, 0.f);
    float  sc = 0.f;
    if (tid < skept) {
      int i = skeeplist[tid];
      bx = boxes[img * PRE + i];
      sc = scores[img * PRE + i];
    }
    float* o = out + ((size_t)img * POST + tid) * 5;
    o[0] = bx.x; o[1] = bx.y; o[2] = bx.z; o[3] = bx.w; o[4] = sc;
  }
}

extern "C" void kernel_launch(void* const* d_in, const int* in_sizes, int n_in,
                              void* d_out, int out_size, void* d_ws, size_t ws_size,
                              hipStream_t stream) {
  const float* logits  = (const float*)d_in[0];
  const float* deltas  = (const float*)d_in[1];
  const float* anchors = (const float*)d_in[2];
  float* out = (float*)d_out;
  char* ws = (char*)d_ws;

  u32* cnt      = (u32*)(ws + CNT_OFF);
  u64* validw   = (u64*)(ws + VALID_OFF);
  u32* phist    = (u32*)(ws + PHIST_OFF);
  u32* pcoarse  = (u32*)(ws + PCOARSE_OFF);
  float4* boxes = (float4*)(ws + BOX_OFF);
  float* scores = (float*)(ws + SCORE_OFF);
  u64* cand     = (u64*)(ws + CAND_OFF);
  u64* mask     = (u64*)(ws + MASK_OFF);

  dim3 gh(CHUNK_H, B_IMG);
  k_hist<<<gh, 256, 0, stream>>>(logits, phist, pcoarse, cnt, validw);
  dim3 gc(CHUNK_C, B_IMG);
  k_compact<<<gc, 256, 0, stream>>>(logits, phist, pcoarse, cnt, cand);
  dim3 gr(RBLK, B_IMG);
  k_rank<<<gr, 256, 0, stream>>>(deltas, anchors, cnt, cand, boxes, scores, validw);
  dim3 g2(16, B_IMG);
  k_iou<<<g2, 1024, 0, stream>>>(boxes, mask);
  k_nms<<<B_IMG, NMS_T, 0, stream>>>(mask, validw, boxes, scores, out);
}

// Round 4
// 200.393 us; speedup vs baseline: 1.0490x; 1.0490x over previous
//
#include <hip/hip_runtime.h>
#include <stdint.h>
#include <math.h>

typedef unsigned long long u64;
typedef unsigned int u32;

#define NPI   360000
#define B_IMG 8
#define PRE   1000
#define POST  300
#define CAP   4096
#define NMSF  0.7f
#define IMG_W 800.0f
#define IMG_H 800.0f

#define NBIN    4096          // 12-bit sortable-key histogram (fallback path)
#define KSHIFT  20            // fkey >> 20 -> 12-bit bin
#define NGRP    64            // coarse groups (fallback select)
#define CHUNK_C 48            // compact blocks per image
#define F4PB_C  (NPI / 4 / CHUNK_C)   // 1875
#define EPB_C   (NPI / CHUNK_C)       // 7500
#define PBLK    128           // per-compact-block candidate region (16-sigma headroom)

// Fixed conservative threshold: logit >= 2.62 -> E[count] ~ 1584 per image
// (>=PRE by 14 sigma, <=CAP by 60 sigma). k_rank VALIDATES the counts and
// falls back to an exact histogram-select recompute if ever violated.
#define THR_LOGIT 2.62f

// ---- workspace layout (bytes) ----
#define VALID_OFF   256               // 8*16*8 = 1024          -> 1280
#define BCNT_OFF    4096              // 8*48*4 = 1536          -> 5632
#define PCAND_OFF   8192              // 8*48*128*8 = 393216    -> 401408
#define BOX_OFF     401408            // 8*1000*16   = 128000   -> 529408
#define SCORE_OFF   529408            // 8*1000*4    = 32000    -> 561408
#define MASK_OFF    561408            // 8*1000*16*8 = 1024000  -> 1585408

#define LDSROWS 496
#define NMS_T   320
#define RBLK    16            // rank blocks per image (256 candidate slots each)

__device__ __forceinline__ u32 fkey(float f) {
  u32 u = __float_as_uint(f);
  return (u & 0x80000000u) ? ~u : (u | 0x80000000u);  // ascending-order bits
}
__device__ __forceinline__ u64 rl64(u64 v, int lane) {
  u32 lo = (u32)__builtin_amdgcn_readlane((int)(u32)v, lane);
  u32 hi = (u32)__builtin_amdgcn_readlane((int)(u32)(v >> 32), lane);
  return ((u64)hi << 32) | lo;
}
__device__ __forceinline__ u64 sx64(u64 v, int m) {
  u32 lo = (u32)__shfl_xor((int)(u32)v, m, 64);
  u32 hi = (u32)__shfl_xor((int)(u32)(v >> 32), m, 64);
  return ((u64)hi << 32) | lo;
}

// ---- K1: compact candidates with fkey >= FK0 into per-block regions.
//      No histogram pass, no global atomics, no pre-zeroed counters. ----
__global__ __launch_bounds__(256) void k_compact(const float* __restrict__ logits,
                                                 u32* __restrict__ bcnt_blk,
                                                 u64* __restrict__ pcand,
                                                 u64* __restrict__ validw) {
  __shared__ u32 bcnt;
  const int img = blockIdx.y, c = blockIdx.x;
  const int t = threadIdx.x;
  const u32 FK0 = fkey(THR_LOGIT);
  if (t == 0) bcnt = 0;
  if (c == 0 && t < 16) validw[img * 16 + t] = 0;   // consumed by k_rank (next dispatch)
  __syncthreads();
  const float4* L = (const float4*)(logits + (size_t)img * NPI) + (size_t)c * F4PB_C;
  u64* P = pcand + ((size_t)img * CHUNK_C + c) * PBLK;
  const int ebase = c * EPB_C;
#pragma unroll
  for (int k = 0; k < 8; k++) {
    int i = t + k * 256;
    if (i < F4PB_C) {
      float4 v = L[i];
      float xs[4] = {v.x, v.y, v.z, v.w};
#pragma unroll
      for (int q = 0; q < 4; q++) {
        float x = xs[q];
        if (fkey(x) >= FK0) {
          // fp32 sigmoid with correctly-rounded exp: replicates numpy f32
          // tie structure exactly (verified: absmax 0.0)
          float ef = (float)exp(-(double)x);
          float sg = 1.0f / (1.0f + ef);
          u32 e = (u32)(ebase + 4 * i + q);
          u32 p = atomicAdd(&bcnt, 1u);
          if (p < PBLK)
            P[p] = ((u64)fkey(sg) << 32) | (u64)(0xFFFFFFFFu - e);
        }
      }
    }
  }
  __syncthreads();
  if (t == 0) bcnt_blk[img * CHUNK_C + c] = bcnt;   // uncapped (overflow detection)
}

// ---- emit one ranked candidate (numerics identical to ref) ----
__device__ __forceinline__ void emit_row(
    int img, int row, u64 key,
    const float* __restrict__ deltas, const float* __restrict__ anchors,
    float4* __restrict__ boxes, float* __restrict__ scores, u64* __restrict__ validw) {
  u32 hi  = (u32)(key >> 32);
  u32 idx = 0xFFFFFFFFu - (u32)(key & 0xFFFFFFFFu);
  u32 su  = (hi & 0x80000000u) ? (hi ^ 0x80000000u) : ~hi;
  float sc = __uint_as_float(su);
  size_t off = (size_t)img * NPI + idx;
  float4 d = ((const float4*)deltas)[off];
  float4 a = ((const float4*)anchors)[off];
  float aw = a.z - a.x, ah = a.w - a.y;
  float acx = a.x + 0.5f * aw, acy = a.y + 0.5f * ah;
  float cx = d.x * aw + acx, cy = d.y * ah + acy;
  float w = expf(d.z) * aw, h = expf(d.w) * ah;
  float x1 = cx - 0.5f * w, y1 = cy - 0.5f * h;
  float x2 = cx + 0.5f * w, y2 = cy + 0.5f * h;
  x1 = fminf(fmaxf(x1, 0.f), IMG_W);
  y1 = fminf(fmaxf(y1, 0.f), IMG_H);
  x2 = fminf(fmaxf(x2, 0.f), IMG_W);
  y2 = fminf(fmaxf(y2, 0.f), IMG_H);
  boxes[img * PRE + row]  = make_float4(x1, y1, x2, y2);
  scores[img * PRE + row] = sc;
  if (((x2 - x1) >= 1e-3f) && ((y2 - y1) >= 1e-3f))
    atomicOr(&validw[img * 16 + (row >> 6)], 1ull << (row & 63));
}

// ---- K2: validate counts, gather candidate regions -> LDS, exact rank +
//      decode/clip. Exact histogram fallback if fixed threshold misbehaves. ----
__global__ __launch_bounds__(256) void k_rank(
    const float* __restrict__ logits,
    const float* __restrict__ deltas, const float* __restrict__ anchors,
    const u32* __restrict__ bcnt_blk, const u64* __restrict__ pcand,
    float4* __restrict__ boxes, float* __restrict__ scores, u64* __restrict__ validw) {
  __shared__ u64 skey[CAP];           // 32 KB (fallback aliases first 16 KB as hist)
  __shared__ u32 pc[4][256];          // per-wave partial counts
  __shared__ u32 scnt[CHUNK_C], soff[CHUNK_C];
  __shared__ int sn, sbad, stb;
  __shared__ u32 rc;
  const int img = blockIdx.y;
  const int tid = threadIdx.x;
  const int w = tid >> 6, l = tid & 63;
  if (tid < CHUNK_C) scnt[tid] = bcnt_blk[img * CHUNK_C + tid];
  if (tid == 0) { sbad = 0; stb = 0; rc = 0; }
  __syncthreads();
  if (tid < 64) {
    u32 m = (tid < CHUNK_C) ? (scnt[tid] > (u32)PBLK ? (u32)PBLK : scnt[tid]) : 0u;
    u64 bb = __ballot(tid < CHUNK_C && scnt[tid] > (u32)PBLK);   // region overflow?
    u32 x = m;
#pragma unroll
    for (int off = 1; off < 64; off <<= 1) {
      u32 o = (u32)__shfl_up((int)x, off, 64);
      if (l >= off) x += o;
    }
    if (tid < CHUNK_C) soff[tid] = x - m;     // exclusive prefix
    u32 tot = (u32)__builtin_amdgcn_readlane((int)x, 63);
    if (tid == 0) {
      sn = (int)tot;
      if (bb != 0ull || tot < (u32)PRE || tot > (u32)CAP) sbad = 1;
    }
  }
  __syncthreads();
  int n = sn;
  if (!sbad) {
    // deterministic gather -> identical skey across all blocks of this image
    for (int c = w; c < CHUNK_C; c += 4) {
      u32 mc = scnt[c];
      u32 off = soff[c];
      const u64* src = pcand + ((size_t)img * CHUNK_C + c) * PBLK;
      for (u32 j = l; j < mc; j += 64) skey[off + j] = src[j];
    }
    __syncthreads();
  } else {
    // ===== exact fallback: rebuild hist, exact threshold bin, recompact =====
    // (never taken for the benchmark distribution; bit-exact if taken)
    u32* hh = (u32*)skey;             // alias first 16 KB
    for (int i = tid; i < NBIN; i += 256) hh[i] = 0;
    __syncthreads();
    const float4* L = (const float4*)(logits + (size_t)img * NPI);
    for (int i = tid; i < NPI / 4; i += 256) {
      float4 v = L[i];
      atomicAdd(&hh[fkey(v.x) >> KSHIFT], 1u);
      atomicAdd(&hh[fkey(v.y) >> KSHIFT], 1u);
      atomicAdd(&hh[fkey(v.z) >> KSHIFT], 1u);
      atomicAdd(&hh[fkey(v.w) >> KSHIFT], 1u);
    }
    __syncthreads();
    if (tid < 64) {
      u32 cg = 0;
      for (int b = 0; b < NBIN / NGRP; b++) cg += hh[tid * (NBIN / NGRP) + b];
      u32 suf = cg;
#pragma unroll
      for (int off = 1; off < 64; off <<= 1) {
        u32 o = (u32)__shfl_down((int)suf, off, 64);
        if (tid + off < 64) suf += o;
      }
      u32 sx = suf - cg;
      u64 bal = __ballot(suf >= (u32)PRE && sx < (u32)PRE);
      if (bal) {
        int gc = __builtin_ctzll(bal);
        u32 s_above = (u32)__shfl((int)sx, gc, 64);
        u32 fb = hh[gc * (NBIN / NGRP) + tid];
        u32 fsuf = fb;
#pragma unroll
        for (int off = 1; off < 64; off <<= 1) {
          u32 o = (u32)__shfl_down((int)fsuf, off, 64);
          if (tid + off < 64) fsuf += o;
        }
        u32 fincl = fsuf + s_above, fexcl = fincl - fb;
        if (fincl >= (u32)PRE && fexcl < (u32)PRE) stb = gc * (NBIN / NGRP) + tid;
      }
    }
    __syncthreads();
    const int tb = stb;
    for (int i = tid; i < NPI / 4; i += 256) {
      float4 v = L[i];
      float xs[4] = {v.x, v.y, v.z, v.w};
#pragma unroll
      for (int q = 0; q < 4; q++) {
        float x = xs[q];
        if ((int)(fkey(x) >> KSHIFT) >= tb) {
          float ef = (float)exp(-(double)x);
          float sg = 1.0f / (1.0f + ef);
          u32 e = (u32)(4 * i + q);
          u32 p = atomicAdd(&rc, 1u);
          if (p < CAP) skey[p] = ((u64)fkey(sg) << 32) | (u64)(0xFFFFFFFFu - e);
        }
      }
    }
    __syncthreads();
    n = (int)(rc < (u32)CAP ? rc : (u32)CAP);
    // per-block skey ORDER is nondeterministic here -> every block redundantly
    // ranks ALL entries (identical idempotent writes; correct, slow, never hit)
    for (int r = tid; r < n; r += 256) {
      u64 kr = skey[r];
      int cr = 0;
      for (int j = 0; j < n; j++) cr += (skey[j] > kr);
      if (cr < PRE) emit_row(img, cr, kr, deltas, anchors, boxes, scores, validw);
    }
    return;
  }
  // ---- fast path: windowed exact rank, count loop sliced across 4 waves ----
  const int base = blockIdx.x * 256;
  if (base >= n) return;              // block-uniform early exit
  const int r0 = base + l, r1 = r0 + 64, r2 = r0 + 128, r3 = r0 + 192;
  u64 k0 = (r0 < n) ? skey[r0] : 0ull;
  u64 k1 = (r1 < n) ? skey[r1] : 0ull;
  u64 k2 = (r2 < n) ? skey[r2] : 0ull;
  u64 k3 = (r3 < n) ? skey[r3] : 0ull;
  int c0 = 0, c1 = 0, c2 = 0, c3 = 0;
  const int js = (w * n) >> 2, je = ((w + 1) * n) >> 2;   // disjoint cover of [0,n)
  for (int j = js; j < je; j++) {
    u64 kj = skey[j];                 // uniform address -> LDS broadcast
    c0 += (kj > k0); c1 += (kj > k1); c2 += (kj > k2); c3 += (kj > k3);
  }
  pc[w][l]       = (u32)c0;
  pc[w][l + 64]  = (u32)c1;
  pc[w][l + 128] = (u32)c2;
  pc[w][l + 192] = (u32)c3;
  __syncthreads();
  const int rr = base + tid;
  if (rr < n) {
    int c = (int)(pc[0][tid] + pc[1][tid] + pc[2][tid] + pc[3][tid]);
    if (c < PRE) emit_row(img, c, skey[rr], deltas, anchors, boxes, scores, validw);
  }
}

// ---- K3: suppression bitmask. 256 blocks (1/CU, 2 waves/SIMD) x 512 thr;
//      32 rows x 16 words per block; dead (upper-triangle) words store 0. ----
__global__ __launch_bounds__(512) void k_iou(const float4* __restrict__ boxes,
                                             u64* __restrict__ mask) {
  __shared__ float4 sb[1024];
  __shared__ float  sa[1024];
  const int img = blockIdx.y, rb = blockIdx.x;   // rb: 32-row block 0..31
  const int tid = threadIdx.x;
  for (int j = tid; j < 1024; j += 512) {
    float4 b = (j < PRE) ? boxes[img * PRE + j] : make_float4(0.f, 0.f, 0.f, 0.f);
    sb[j] = b;
    sa[j] = (b.z - b.x) * (b.w - b.y);
  }
  __syncthreads();
  const int i  = rb * 32 + (tid & 31);   // row 0..1023
  const int wv = tid >> 5;               // word 0..15
  const bool rowok = (i < PRE);
  const int cbase = wv << 6;
  if (cbase + 63 < rb * 32) {            // whole word < every row in block -> masked out
    if (rowok) mask[((size_t)img * PRE + i) * 16 + wv] = 0ull;
    return;
  }
  const float4 bi = sb[i];
  const float  ai = sa[i];
  u64 bits = 0;
#pragma unroll
  for (int k = 0; k < 64; k++) {
    int c = cbase + k;
    float4 bc = sb[c];                   // half-wave-uniform broadcast read
    float ac  = sa[c];
    float ltx = fmaxf(bi.x, bc.x), lty = fmaxf(bi.y, bc.y);
    float rbx = fminf(bi.z, bc.z), rby = fminf(bi.w, bc.w);
    float iw = fmaxf(rbx - ltx, 0.f), ih = fmaxf(rby - lty, 0.f);
    float inter = iw * ih;
    float iou = inter / (ai + ac - inter + 1e-9f);  // IEEE div, matches ref
    bits |= (iou > NMSF) ? (1ull << k) : 0ull;
  }
  int d = i - cbase;
  u64 gtmask = (d < 0) ? ~0ull : ((d >= 63) ? 0ull : (~0ull << (d + 1)));
  int rem = PRE - cbase;
  u64 tmask = (rem >= 64) ? ~0ull : ((rem <= 0) ? 0ull : ((1ull << rem) - 1ull));
  bits &= gtmask & tmask;
  if (rowok) mask[((size_t)img * PRE + i) * 16 + wv] = bits;
}

// ---- K4: chunked greedy scan — scalar in-chunk decisions via readlane ----
__global__ __launch_bounds__(NMS_T) void k_nms(
    const u64* __restrict__ mask, const u64* __restrict__ validw,
    const float4* __restrict__ boxes, const float* __restrict__ scores,
    float* __restrict__ out) {
  __shared__ u64 smask[LDSROWS * 16];
  __shared__ int skeeplist[POST];
  __shared__ int skept;
  const int img = blockIdx.x;
  const int tid = threadIdx.x;
  const u64* M = mask + (size_t)img * PRE * 16;
  u64 diag[16];
  if (tid < 64) {
#pragma unroll
    for (int cc = 0; cc < 16; cc++) {
      int row = cc * 64 + tid;
      diag[cc] = (row < PRE) ? M[(size_t)row * 16 + cc] : 0ull;
    }
  }
  for (int e = tid; e < LDSROWS * 16; e += NMS_T) smask[e] = M[e];
  __syncthreads();
  if (tid < 64) {
    const int lane = tid;
    const int w = lane & 15, g = lane >> 4;
    u64 rem = ~0ull;
    if (lane < 16) {
      rem = ~validw[img * 16 + lane];
      if (lane == 15) rem |= 0xFFFFFF0000000000ull;  // rows 1000..1023 invalid
    }
    int kept = 0;
#pragma unroll
    for (int cc = 0; cc < 16; cc++) {
      u64 alive = ~rl64(rem, cc);      // wave-uniform
      int kept0 = kept;
      while (alive != 0ull && kept < POST) {
        int r = __builtin_ctzll(alive);
        if (lane == 0) skeeplist[kept] = cc * 64 + r;
        kept++;
        u64 sup = rl64(diag[cc], r);   // row's in-chunk suppression word
        alive &= ~sup;
        alive &= ~(1ull << r);
      }
      int nc = kept - kept0;
      if (nc > 0 && kept < POST && cc < 15) {
        u64 part = 0;
        for (int j = g; j < nc; j += 4) {
          int row = skeeplist[kept0 + j];
          part |= (row < LDSROWS) ? smask[row * 16 + w] : M[(size_t)row * 16 + w];
        }
        part |= sx64(part, 16);
        part |= sx64(part, 32);
        rem |= part;                   // only lanes <16 meaningful
      }
      if (kept >= POST) break;
    }
    if (lane == 0) skept = kept;
  }
  __syncthreads();
  if (tid < POST) {
    float4 bx = make_float4(0.f, 0.f, 0.f, 0.f);
    float  sc = 0.f;
    if (tid < skept) {
      int i = skeeplist[tid];
      bx = boxes[img * PRE + i];
      sc = scores[img * PRE + i];
    }
    float* o = out + ((size_t)img * POST + tid) * 5;
    o[0] = bx.x; o[1] = bx.y; o[2] = bx.z; o[3] = bx.w; o[4] = sc;
  }
}

extern "C" void kernel_launch(void* const* d_in, const int* in_sizes, int n_in,
                              void* d_out, int out_size, void* d_ws, size_t ws_size,
                              hipStream_t stream) {
  const float* logits  = (const float*)d_in[0];
  const float* deltas  = (const float*)d_in[1];
  const float* anchors = (const float*)d_in[2];
  float* out = (float*)d_out;
  char* ws = (char*)d_ws;

  u64* validw   = (u64*)(ws + VALID_OFF);
  u32* bcnt_blk = (u32*)(ws + BCNT_OFF);
  u64* pcand    = (u64*)(ws + PCAND_OFF);
  float4* boxes = (float4*)(ws + BOX_OFF);
  float* scores = (float*)(ws + SCORE_OFF);
  u64* mask     = (u64*)(ws + MASK_OFF);

  dim3 gc(CHUNK_C, B_IMG);
  k_compact<<<gc, 256, 0, stream>>>(logits, bcnt_blk, pcand, validw);
  dim3 gr(RBLK, B_IMG);
  k_rank<<<gr, 256, 0, stream>>>(logits, deltas, anchors, bcnt_blk, pcand,
                                 boxes, scores, validw);
  dim3 g2(32, B_IMG);
  k_iou<<<g2, 512, 0, stream>>>(boxes, mask);
  k_nms<<<B_IMG, NMS_T, 0, stream>>>(mask, validw, boxes, scores, out);
}

// Round 5
// 183.114 us; speedup vs baseline: 1.1479x; 1.0944x over previous
//
#include <hip/hip_runtime.h>
#include <stdint.h>
#include <math.h>

typedef unsigned long long u64;
typedef unsigned int u32;

#define NPI   360000
#define B_IMG 8
#define PRE   1000
#define POST  300
#define CAP   4096
#define NMSF  0.7f
#define IMG_W 800.0f
#define IMG_H 800.0f

#define NBIN    4096          // 12-bit sortable-key histogram (fallback path)
#define KSHIFT  20            // fkey >> 20 -> 12-bit bin
#define NGRP    64            // coarse groups (fallback select)
#define CHUNK_C 48            // compact blocks per image
#define F4PB_C  (NPI / 4 / CHUNK_C)   // 1875
#define EPB_C   (NPI / CHUNK_C)       // 7500
#define PBLK    128           // per-compact-block candidate region (16-sigma headroom)

// Fixed conservative threshold: logit >= 2.62 -> E[count] ~ 1584 per image
// (>=PRE by 14 sigma, <=CAP by 60 sigma). k_rank VALIDATES the counts and
// falls back to an exact histogram-select recompute if ever violated.
#define THR_LOGIT 2.62f

// ---- workspace layout (bytes) ----
#define VALID_OFF   256               // 8*16*8 = 1024          -> 1280
#define BCNT_OFF    4096              // 8*48*4 = 1536          -> 5632
#define PCAND_OFF   8192              // 8*48*128*8 = 393216    -> 401408
#define BOX_OFF     401408            // 8*1000*16   = 128000   -> 529408
#define SCORE_OFF   529408            // 8*1000*4    = 32000    -> 561408
#define MASK_OFF    561408            // 8*1000*16*8 = 1024000  -> 1585408

#define LDSROWS 496
#define NMS_T   320
#define RBLK    16            // rank blocks per image (256 candidate slots each)

__device__ __forceinline__ u32 fkey(float f) {
  u32 u = __float_as_uint(f);
  return (u & 0x80000000u) ? ~u : (u | 0x80000000u);  // ascending-order bits
}
__device__ __forceinline__ u64 rl64(u64 v, int lane) {
  u32 lo = (u32)__builtin_amdgcn_readlane((int)(u32)v, lane);
  u32 hi = (u32)__builtin_amdgcn_readlane((int)(u32)(v >> 32), lane);
  return ((u64)hi << 32) | lo;
}
__device__ __forceinline__ u64 sx64(u64 v, int m) {
  u32 lo = (u32)__shfl_xor((int)(u32)v, m, 64);
  u32 hi = (u32)__shfl_xor((int)(u32)(v >> 32), m, 64);
  return ((u64)hi << 32) | lo;
}

// ---- K1: compact candidates with fkey >= FK0 into per-block regions.
//      No histogram pass, no global atomics, no pre-zeroed counters. ----
__global__ __launch_bounds__(256) void k_compact(const float* __restrict__ logits,
                                                 u32* __restrict__ bcnt_blk,
                                                 u64* __restrict__ pcand,
                                                 u64* __restrict__ validw) {
  __shared__ u32 bcnt;
  const int img = blockIdx.y, c = blockIdx.x;
  const int t = threadIdx.x;
  const u32 FK0 = fkey(THR_LOGIT);
  if (t == 0) bcnt = 0;
  if (c == 0 && t < 16) validw[img * 16 + t] = 0;   // consumed by k_rank (next dispatch)
  __syncthreads();
  const float4* L = (const float4*)(logits + (size_t)img * NPI) + (size_t)c * F4PB_C;
  u64* P = pcand + ((size_t)img * CHUNK_C + c) * PBLK;
  const int ebase = c * EPB_C;
#pragma unroll
  for (int k = 0; k < 8; k++) {
    int i = t + k * 256;
    if (i < F4PB_C) {
      float4 v = L[i];
      float xs[4] = {v.x, v.y, v.z, v.w};
#pragma unroll
      for (int q = 0; q < 4; q++) {
        float x = xs[q];
        if (fkey(x) >= FK0) {
          // fp32 sigmoid with correctly-rounded exp: replicates numpy f32
          // tie structure exactly (verified: absmax 0.0)
          float ef = (float)exp(-(double)x);
          float sg = 1.0f / (1.0f + ef);
          u32 e = (u32)(ebase + 4 * i + q);
          u32 p = atomicAdd(&bcnt, 1u);
          if (p < PBLK)
            P[p] = ((u64)fkey(sg) << 32) | (u64)(0xFFFFFFFFu - e);
        }
      }
    }
  }
  __syncthreads();
  if (t == 0) bcnt_blk[img * CHUNK_C + c] = bcnt;   // uncapped (overflow detection)
}

// ---- emit one ranked candidate (numerics identical to ref) ----
__device__ __forceinline__ void emit_row(
    int img, int row, u64 key,
    const float* __restrict__ deltas, const float* __restrict__ anchors,
    float4* __restrict__ boxes, float* __restrict__ scores, u64* __restrict__ validw) {
  u32 hi  = (u32)(key >> 32);
  u32 idx = 0xFFFFFFFFu - (u32)(key & 0xFFFFFFFFu);
  u32 su  = (hi & 0x80000000u) ? (hi ^ 0x80000000u) : ~hi;
  float sc = __uint_as_float(su);
  size_t off = (size_t)img * NPI + idx;
  float4 d = ((const float4*)deltas)[off];
  float4 a = ((const float4*)anchors)[off];
  float aw = a.z - a.x, ah = a.w - a.y;
  float acx = a.x + 0.5f * aw, acy = a.y + 0.5f * ah;
  float cx = d.x * aw + acx, cy = d.y * ah + acy;
  float w = expf(d.z) * aw, h = expf(d.w) * ah;
  float x1 = cx - 0.5f * w, y1 = cy - 0.5f * h;
  float x2 = cx + 0.5f * w, y2 = cy + 0.5f * h;
  x1 = fminf(fmaxf(x1, 0.f), IMG_W);
  y1 = fminf(fmaxf(y1, 0.f), IMG_H);
  x2 = fminf(fmaxf(x2, 0.f), IMG_W);
  y2 = fminf(fmaxf(y2, 0.f), IMG_H);
  boxes[img * PRE + row]  = make_float4(x1, y1, x2, y2);
  scores[img * PRE + row] = sc;
  if (((x2 - x1) >= 1e-3f) && ((y2 - y1) >= 1e-3f))
    atomicOr(&validw[img * 16 + (row >> 6)], 1ull << (row & 63));
}

// ---- K2: validate counts, gather candidate regions -> LDS, exact rank +
//      decode/clip. Count loop 8-way load-batched (breaks the ds_read
//      latency chain: 8 independent LDS reads in flight per iteration). ----
__global__ __launch_bounds__(256) void k_rank(
    const float* __restrict__ logits,
    const float* __restrict__ deltas, const float* __restrict__ anchors,
    const u32* __restrict__ bcnt_blk, const u64* __restrict__ pcand,
    float4* __restrict__ boxes, float* __restrict__ scores, u64* __restrict__ validw) {
  __shared__ u64 skey[CAP];           // 32 KB (fallback aliases first 16 KB as hist)
  __shared__ u32 pc[4][256];          // per-wave partial counts
  __shared__ u32 scnt[CHUNK_C], soff[CHUNK_C];
  __shared__ int sn, sbad, stb;
  __shared__ u32 rc;
  const int img = blockIdx.y;
  const int tid = threadIdx.x;
  const int w = tid >> 6, l = tid & 63;
  if (tid < CHUNK_C) scnt[tid] = bcnt_blk[img * CHUNK_C + tid];
  if (tid == 0) { sbad = 0; stb = 0; rc = 0; }
  __syncthreads();
  if (tid < 64) {
    u32 m = (tid < CHUNK_C) ? (scnt[tid] > (u32)PBLK ? (u32)PBLK : scnt[tid]) : 0u;
    u64 bb = __ballot(tid < CHUNK_C && scnt[tid] > (u32)PBLK);   // region overflow?
    u32 x = m;
#pragma unroll
    for (int off = 1; off < 64; off <<= 1) {
      u32 o = (u32)__shfl_up((int)x, off, 64);
      if (l >= off) x += o;
    }
    if (tid < CHUNK_C) soff[tid] = x - m;     // exclusive prefix
    u32 tot = (u32)__builtin_amdgcn_readlane((int)x, 63);
    if (tid == 0) {
      sn = (int)tot;
      if (bb != 0ull || tot < (u32)PRE || tot > (u32)CAP) sbad = 1;
    }
  }
  __syncthreads();
  int n = sn;
  const int base = blockIdx.x * 256;
  if (!sbad) {
    if (base >= n) return;            // block-uniform early exit BEFORE gather
    // deterministic gather -> identical skey across all blocks of this image
    for (int c = w; c < CHUNK_C; c += 4) {
      u32 mc = scnt[c];
      u32 off = soff[c];
      const u64* src = pcand + ((size_t)img * CHUNK_C + c) * PBLK;
      for (u32 j = l; j < mc; j += 64) skey[off + j] = src[j];
    }
    __syncthreads();
  } else {
    // ===== exact fallback: rebuild hist, exact threshold bin, recompact =====
    // (never taken for the benchmark distribution; bit-exact if taken)
    u32* hh = (u32*)skey;             // alias first 16 KB
    for (int i = tid; i < NBIN; i += 256) hh[i] = 0;
    __syncthreads();
    const float4* L = (const float4*)(logits + (size_t)img * NPI);
    for (int i = tid; i < NPI / 4; i += 256) {
      float4 v = L[i];
      atomicAdd(&hh[fkey(v.x) >> KSHIFT], 1u);
      atomicAdd(&hh[fkey(v.y) >> KSHIFT], 1u);
      atomicAdd(&hh[fkey(v.z) >> KSHIFT], 1u);
      atomicAdd(&hh[fkey(v.w) >> KSHIFT], 1u);
    }
    __syncthreads();
    if (tid < 64) {
      u32 cg = 0;
      for (int b = 0; b < NBIN / NGRP; b++) cg += hh[tid * (NBIN / NGRP) + b];
      u32 suf = cg;
#pragma unroll
      for (int off = 1; off < 64; off <<= 1) {
        u32 o = (u32)__shfl_down((int)suf, off, 64);
        if (tid + off < 64) suf += o;
      }
      u32 sx = suf - cg;
      u64 bal = __ballot(suf >= (u32)PRE && sx < (u32)PRE);
      if (bal) {
        int gc = __builtin_ctzll(bal);
        u32 s_above = (u32)__shfl((int)sx, gc, 64);
        u32 fb = hh[gc * (NBIN / NGRP) + tid];
        u32 fsuf = fb;
#pragma unroll
        for (int off = 1; off < 64; off <<= 1) {
          u32 o = (u32)__shfl_down((int)fsuf, off, 64);
          if (tid + off < 64) fsuf += o;
        }
        u32 fincl = fsuf + s_above, fexcl = fincl - fb;
        if (fincl >= (u32)PRE && fexcl < (u32)PRE) stb = gc * (NBIN / NGRP) + tid;
      }
    }
    __syncthreads();
    const int tb = stb;
    for (int i = tid; i < NPI / 4; i += 256) {
      float4 v = L[i];
      float xs[4] = {v.x, v.y, v.z, v.w};
#pragma unroll
      for (int q = 0; q < 4; q++) {
        float x = xs[q];
        if ((int)(fkey(x) >> KSHIFT) >= tb) {
          float ef = (float)exp(-(double)x);
          float sg = 1.0f / (1.0f + ef);
          u32 e = (u32)(4 * i + q);
          u32 p = atomicAdd(&rc, 1u);
          if (p < CAP) skey[p] = ((u64)fkey(sg) << 32) | (u64)(0xFFFFFFFFu - e);
        }
      }
    }
    __syncthreads();
    n = (int)(rc < (u32)CAP ? rc : (u32)CAP);
    // per-block skey ORDER is nondeterministic here -> every block redundantly
    // ranks ALL entries (identical idempotent writes; correct, slow, never hit)
    for (int r = tid; r < n; r += 256) {
      u64 kr = skey[r];
      int cr = 0;
      for (int j = 0; j < n; j++) cr += (skey[j] > kr);
      if (cr < PRE) emit_row(img, cr, kr, deltas, anchors, boxes, scores, validw);
    }
    return;
  }
  // ---- fast path: windowed exact rank, sliced across 4 waves, loads
  //      batched 8-wide so the LDS reads pipeline instead of serializing ----
  const int r0 = base + l, r1 = r0 + 64, r2 = r0 + 128, r3 = r0 + 192;
  u64 k0 = (r0 < n) ? skey[r0] : 0ull;
  u64 k1 = (r1 < n) ? skey[r1] : 0ull;
  u64 k2 = (r2 < n) ? skey[r2] : 0ull;
  u64 k3 = (r3 < n) ? skey[r3] : 0ull;
  int c0 = 0, c1 = 0, c2 = 0, c3 = 0;
  const int js = (w * n) >> 2, je = ((w + 1) * n) >> 2;   // disjoint cover of [0,n)
  int j = js;
  for (; j + 8 <= je; j += 8) {
    u64 b0 = skey[j + 0], b1 = skey[j + 1], b2 = skey[j + 2], b3 = skey[j + 3];
    u64 b4 = skey[j + 4], b5 = skey[j + 5], b6 = skey[j + 6], b7 = skey[j + 7];
    c0 += (b0 > k0) + (b1 > k0) + (b2 > k0) + (b3 > k0)
        + (b4 > k0) + (b5 > k0) + (b6 > k0) + (b7 > k0);
    c1 += (b0 > k1) + (b1 > k1) + (b2 > k1) + (b3 > k1)
        + (b4 > k1) + (b5 > k1) + (b6 > k1) + (b7 > k1);
    c2 += (b0 > k2) + (b1 > k2) + (b2 > k2) + (b3 > k2)
        + (b4 > k2) + (b5 > k2) + (b6 > k2) + (b7 > k2);
    c3 += (b0 > k3) + (b1 > k3) + (b2 > k3) + (b3 > k3)
        + (b4 > k3) + (b5 > k3) + (b6 > k3) + (b7 > k3);
  }
  for (; j < je; j++) {
    u64 kj = skey[j];
    c0 += (kj > k0); c1 += (kj > k1); c2 += (kj > k2); c3 += (kj > k3);
  }
  pc[w][l]       = (u32)c0;
  pc[w][l + 64]  = (u32)c1;
  pc[w][l + 128] = (u32)c2;
  pc[w][l + 192] = (u32)c3;
  __syncthreads();
  const int rr = base + tid;
  if (rr < n) {
    int c = (int)(pc[0][tid] + pc[1][tid] + pc[2][tid] + pc[3][tid]);
    if (c < PRE) emit_row(img, c, skey[rr], deltas, anchors, boxes, scores, validw);
  }
}

// ---- K3: suppression bitmask. 256 blocks (1/CU, 2 waves/SIMD) x 512 thr;
//      32 rows x 16 words per block; dead (upper-triangle) words store 0. ----
__global__ __launch_bounds__(512) void k_iou(const float4* __restrict__ boxes,
                                             u64* __restrict__ mask) {
  __shared__ float4 sb[1024];
  __shared__ float  sa[1024];
  const int img = blockIdx.y, rb = blockIdx.x;   // rb: 32-row block 0..31
  const int tid = threadIdx.x;
  for (int j = tid; j < 1024; j += 512) {
    float4 b = (j < PRE) ? boxes[img * PRE + j] : make_float4(0.f, 0.f, 0.f, 0.f);
    sb[j] = b;
    sa[j] = (b.z - b.x) * (b.w - b.y);
  }
  __syncthreads();
  const int i  = rb * 32 + (tid & 31);   // row 0..1023
  const int wv = tid >> 5;               // word 0..15
  const bool rowok = (i < PRE);
  const int cbase = wv << 6;
  if (cbase + 63 < rb * 32) {            // whole word < every row in block -> masked out
    if (rowok) mask[((size_t)img * PRE + i) * 16 + wv] = 0ull;
    return;
  }
  const float4 bi = sb[i];
  const float  ai = sa[i];
  u64 bits = 0;
#pragma unroll
  for (int k = 0; k < 64; k++) {
    int c = cbase + k;
    float4 bc = sb[c];                   // half-wave-uniform broadcast read
    float ac  = sa[c];
    float ltx = fmaxf(bi.x, bc.x), lty = fmaxf(bi.y, bc.y);
    float rbx = fminf(bi.z, bc.z), rby = fminf(bi.w, bc.w);
    float iw = fmaxf(rbx - ltx, 0.f), ih = fmaxf(rby - lty, 0.f);
    float inter = iw * ih;
    float iou = inter / (ai + ac - inter + 1e-9f);  // IEEE div, matches ref
    bits |= (iou > NMSF) ? (1ull << k) : 0ull;
  }
  int d = i - cbase;
  u64 gtmask = (d < 0) ? ~0ull : ((d >= 63) ? 0ull : (~0ull << (d + 1)));
  int rem = PRE - cbase;
  u64 tmask = (rem >= 64) ? ~0ull : ((rem <= 0) ? 0ull : ((1ull << rem) - 1ull));
  bits &= gtmask & tmask;
  if (rowok) mask[((size_t)img * PRE + i) * 16 + wv] = bits;
}

// ---- K4: chunked greedy scan — scalar in-chunk decisions via readlane ----
__global__ __launch_bounds__(NMS_T) void k_nms(
    const u64* __restrict__ mask, const u64* __restrict__ validw,
    const float4* __restrict__ boxes, const float* __restrict__ scores,
    float* __restrict__ out) {
  __shared__ u64 smask[LDSROWS * 16];
  __shared__ int skeeplist[POST];
  __shared__ int skept;
  const int img = blockIdx.x;
  const int tid = threadIdx.x;
  const u64* M = mask + (size_t)img * PRE * 16;
  u64 diag[16];
  if (tid < 64) {
#pragma unroll
    for (int cc = 0; cc < 16; cc++) {
      int row = cc * 64 + tid;
      diag[cc] = (row < PRE) ? M[(size_t)row * 16 + cc] : 0ull;
    }
  }
  for (int e = tid; e < LDSROWS * 16; e += NMS_T) smask[e] = M[e];
  __syncthreads();
  if (tid < 64) {
    const int lane = tid;
    const int w = lane & 15, g = lane >> 4;
    u64 rem = ~0ull;
    if (lane < 16) {
      rem = ~validw[img * 16 + lane];
      if (lane == 15) rem |= 0xFFFFFF0000000000ull;  // rows 1000..1023 invalid
    }
    int kept = 0;
#pragma unroll
    for (int cc = 0; cc < 16; cc++) {
      u64 alive = ~rl64(rem, cc);      // wave-uniform
      int kept0 = kept;
      while (alive != 0ull && kept < POST) {
        int r = __builtin_ctzll(alive);
        if (lane == 0) skeeplist[kept] = cc * 64 + r;
        kept++;
        u64 sup = rl64(diag[cc], r);   // row's in-chunk suppression word
        alive &= ~sup;
        alive &= ~(1ull << r);
      }
      int nc = kept - kept0;
      if (nc > 0 && kept < POST && cc < 15) {
        u64 part = 0;
        for (int j = g; j < nc; j += 4) {
          int row = skeeplist[kept0 + j];
          part |= (row < LDSROWS) ? smask[row * 16 + w] : M[(size_t)row * 16 + w];
        }
        part |= sx64(part, 16);
        part |= sx64(part, 32);
        rem |= part;                   // only lanes <16 meaningful
      }
      if (kept >= POST) break;
    }
    if (lane == 0) skept = kept;
  }
  __syncthreads();
  if (tid < POST) {
    float4 bx = make_float4(0.f, 0.f, 0.f, 0.f);
    float  sc = 0.f;
    if (tid < skept) {
      int i = skeeplist[tid];
      bx = boxes[img * PRE + i];
      sc = scores[img * PRE + i];
    }
    float* o = out + ((size_t)img * POST + tid) * 5;
    o[0] = bx.x; o[1] = bx.y; o[2] = bx.z; o[3] = bx.w; o[4] = sc;
  }
}

extern "C" void kernel_launch(void* const* d_in, const int* in_sizes, int n_in,
                              void* d_out, int out_size, void* d_ws, size_t ws_size,
                              hipStream_t stream) {
  const float* logits  = (const float*)d_in[0];
  const float* deltas  = (const float*)d_in[1];
  const float* anchors = (const float*)d_in[2];
  float* out = (float*)d_out;
  char* ws = (char*)d_ws;

  u64* validw   = (u64*)(ws + VALID_OFF);
  u32* bcnt_blk = (u32*)(ws + BCNT_OFF);
  u64* pcand    = (u64*)(ws + PCAND_OFF);
  float4* boxes = (float4*)(ws + BOX_OFF);
  float* scores = (float*)(ws + SCORE_OFF);
  u64* mask     = (u64*)(ws + MASK_OFF);

  dim3 gc(CHUNK_C, B_IMG);
  k_compact<<<gc, 256, 0, stream>>>(logits, bcnt_blk, pcand, validw);
  dim3 gr(RBLK, B_IMG);
  k_rank<<<gr, 256, 0, stream>>>(logits, deltas, anchors, bcnt_blk, pcand,
                                 boxes, scores, validw);
  dim3 g2(32, B_IMG);
  k_iou<<<g2, 512, 0, stream>>>(boxes, mask);
  k_nms<<<B_IMG, NMS_T, 0, stream>>>(mask, validw, boxes, scores, out);
}